// Round 5
// baseline (582.266 us; speedup 1.0000x reference)
//
#include <hip/hip_runtime.h>
#include <hip/hip_bf16.h>
#include <math.h>

typedef __attribute__((ext_vector_type(8))) short short8;
typedef __attribute__((ext_vector_type(4))) float f32x4;
typedef __attribute__((ext_vector_type(4))) unsigned int uint4v;

#define KN 100

// ---- ws layout (halfword units) ----
#define W1_OFF 0         // 64x128 bf16, B-frag swizzled, kt=4
#define W2_OFF 8192      // 64x64, kt=2
#define W3_OFF 12288     // 32x64, kt=2
#define W4_OFF 14336     // 32x32, kt=1
#define SCRU_OFF 16384                        // 100000 x 128 bf16 (zero-padded j>=100)
#define SCRI_OFF (SCRU_OFF + 100000 * 128)    // 50000 x 128
#define EMBU_OFF (SCRI_OFF + 50000 * 128)     // 100000 x 64 bf16
#define EMBI_OFF (EMBU_OFF + 100000 * 64)     // 50000 x 64

// ---- LDS: single X buffer [112 rows x 136 stride] (Y layers alias inside) ----
#define XS 136
#define S_TOT (112 * XS)   // 15232 hw = 30464 B

__device__ __forceinline__ unsigned short f2bf(float f) {
  __hip_bfloat16 h = __float2bfloat16(f);
  return __builtin_bit_cast(unsigned short, h);
}

__device__ __forceinline__ void st8(unsigned short* d, float4 a, float4 b) {
  short8 h;
  h[0] = (short)f2bf(a.x); h[1] = (short)f2bf(a.y);
  h[2] = (short)f2bf(a.z); h[3] = (short)f2bf(a.w);
  h[4] = (short)f2bf(b.x); h[5] = (short)f2bf(b.y);
  h[6] = (short)f2bf(b.z); h[7] = (short)f2bf(b.w);
  *reinterpret_cast<short8*>(d) = h;
}

// Streaming prep: weights (B-frag swizzle) + scr (bf16, pad to 128) + emb (bf16).
__global__ void prep(const float* __restrict__ w1, const float* __restrict__ w2,
                     const float* __restrict__ w3, const float* __restrict__ w4,
                     const float* __restrict__ uscr, const float* __restrict__ iscr,
                     const float* __restrict__ uemb, const float* __restrict__ iemb,
                     unsigned short* __restrict__ ws) {
  int t = blockIdx.x * 256 + threadIdx.x;
  if (t < 15360) {
    const float* src; int rel, o, i, kt, base;
    if (t < 8192)       { src = w1; rel = t;         o = rel >> 7; i = rel & 127; kt = 4; base = W1_OFF; }
    else if (t < 12288) { src = w2; rel = t - 8192;  o = rel >> 6; i = rel & 63;  kt = 2; base = W2_OFF; }
    else if (t < 14336) { src = w3; rel = t - 12288; o = rel >> 6; i = rel & 63;  kt = 2; base = W3_OFF; }
    else                { src = w4; rel = t - 14336; o = rel >> 5; i = rel & 31;  kt = 1; base = W4_OFF; }
    int n = o >> 4, l15 = o & 15, k = i >> 5, quad = (i >> 3) & 3, j = i & 7;
    ws[base + ((n * kt + k) * 64 + quad * 16 + l15) * 8 + j] = f2bf(src[rel]);
    return;
  }
  int rel = t - 15360;
  const float4 z4 = {0.f, 0.f, 0.f, 0.f};
  if (rel < 2400000) {  // scr: 16 threads/row, 8 outputs each (128 cols, pad >=100)
    const float* src; unsigned short* dst; int row, g;
    if (rel < 1600000) {
      row = rel >> 4; g = rel & 15;
      src = uscr + (size_t)row * 100;
      dst = ws + SCRU_OFF + (size_t)row * 128 + g * 8;
    } else {
      int q = rel - 1600000; row = q >> 4; g = q & 15;
      src = iscr + (size_t)row * 100;
      dst = ws + SCRI_OFF + (size_t)row * 128 + g * 8;
    }
    float4 va = (g < 13) ? *reinterpret_cast<const float4*>(src + g * 8) : z4;
    float4 vb = (g < 12) ? *reinterpret_cast<const float4*>(src + g * 8 + 4) : z4;
    st8(dst, va, vb);
    return;
  }
  rel -= 2400000;
  if (rel < 1200000) {  // emb: 8 threads/row, 8 outputs each (64 cols)
    const float* src; unsigned short* dst; int row, g;
    if (rel < 800000) {
      row = rel >> 3; g = rel & 7;
      src = uemb + (size_t)row * 64;
      dst = ws + EMBU_OFF + (size_t)row * 64 + g * 8;
    } else {
      int q = rel - 800000; row = q >> 3; g = q & 7;
      src = iemb + (size_t)row * 64;
      dst = ws + EMBI_OFF + (size_t)row * 64 + g * 8;
    }
    float4 va = *reinterpret_cast<const float4*>(src + g * 8);
    float4 vb = *reinterpret_cast<const float4*>(src + g * 8 + 4);
    st8(dst, va, vb);
  }
}

// One MLP layer for wave w's 16-row band of X: Y = relu(A @ W^T + bias).
// A-frags preloaded by caller; W from global ws (L1-hot, frag-contiguous).
template <int NT, int KT>
__device__ __forceinline__ void mlp_layer(const short8* a,
                                          const unsigned short* __restrict__ gw,
                                          const float* __restrict__ bias,
                                          unsigned short* __restrict__ S, int ycol0,
                                          int w, int l15, int quad, int lane) {
#pragma unroll
  for (int n = 0; n < NT; ++n) {
    f32x4 acc = {0.f, 0.f, 0.f, 0.f};
#pragma unroll
    for (int k = 0; k < KT; ++k) {
      short8 bf = *reinterpret_cast<const short8*>(gw + ((n * KT + k) * 64 + lane) * 8);
      acc = __builtin_amdgcn_mfma_f32_16x16x32_bf16(a[k], bf, acc, 0, 0, 0);
    }
    const int col = n * 16 + l15;
    const float bv = bias[col];
#pragma unroll
    for (int r = 0; r < 4; ++r) {
      float v = fmaxf(acc[r] + bv, 0.f);
      S[(w * 16 + quad * 4 + r) * XS + ycol0 + col] = f2bf(v);
    }
  }
}

__launch_bounds__(448, 8)
__global__ void cnn_mfma4(
    const unsigned short* __restrict__ ws,
    const float* __restrict__ b1, const float* __restrict__ b2,
    const float* __restrict__ b3, const float* __restrict__ b4,
    const float* __restrict__ w5, const float* __restrict__ b5,
    const int* __restrict__ user_idx_t, const int* __restrict__ item_idx_t,
    const int* __restrict__ user_idxs, const int* __restrict__ item_idxs,
    float* __restrict__ out) {
  __shared__ __align__(16) unsigned short S[S_TOT];
  __shared__ __align__(16) int s_nb[2][128];
  __shared__ float s_red[7];

  const int b = blockIdx.x;
  const int tid = threadIdx.x;
  const int w = tid >> 6;
  const int lane = tid & 63;
  const int l15 = lane & 15, quad = lane >> 4;

  // ---- neighbor lists, padded with 0 up to 128 (k-dim pad; scr zeros kill
  // the products, m-row pads produce discarded rows) ----
  if (tid < 128) {
    s_nb[0][tid] = (tid < KN) ? user_idx_t[(size_t)user_idxs[b] * KN + tid] : 0;
  } else if (tid < 256) {
    const int i = tid - 128;
    s_nb[1][i] = (i < KN) ? item_idx_t[(size_t)item_idxs[b] * KN + i] : 0;
  }
  __syncthreads();  // barrier #1 (the only one before the final reduce)

  // ---- pooling: X[m][src*64+d] = sum_j scr[nb[m]][j] * emb[nb[j]][d]
  // A-frag from global scr row (16B contiguous); B-frag elements gathered
  // per-lane from global emb (lanes 0-15 cover 32B contiguous per row).
#pragma unroll 1
  for (int src = 0; src < 2; ++src) {
    const char* scrb = (const char*)(ws + (src ? SCRI_OFF : SCRU_OFF));
    const char* embb = (const char*)(ws + (src ? EMBI_OFF : EMBU_OFF));
    const int* nbs = s_nb[src];
    const unsigned int aoff = (unsigned int)nbs[w * 16 + l15] << 8;  // row*256B
    const int xc0 = src * 64;
#pragma unroll
    for (int nt = 0; nt < 4; ++nt) {
      const unsigned int dd = (unsigned int)(nt * 16 + l15) * 2;  // byte offset of d
      f32x4 acc = {0.f, 0.f, 0.f, 0.f};
#pragma unroll
      for (int kt = 0; kt < 4; ++kt) {
        short8 a = *reinterpret_cast<const short8*>(scrb + aoff + kt * 64 + quad * 16);
        const int* np = nbs + kt * 32 + quad * 8;
        const int4 n0 = *reinterpret_cast<const int4*>(np);
        const int4 n1 = *reinterpret_cast<const int4*>(np + 4);
        unsigned short h0 = *(const unsigned short*)(embb + (((unsigned int)n0.x << 7) + dd));
        unsigned short h1 = *(const unsigned short*)(embb + (((unsigned int)n0.y << 7) + dd));
        unsigned short h2 = *(const unsigned short*)(embb + (((unsigned int)n0.z << 7) + dd));
        unsigned short h3 = *(const unsigned short*)(embb + (((unsigned int)n0.w << 7) + dd));
        unsigned short h4 = *(const unsigned short*)(embb + (((unsigned int)n1.x << 7) + dd));
        unsigned short h5 = *(const unsigned short*)(embb + (((unsigned int)n1.y << 7) + dd));
        unsigned short h6 = *(const unsigned short*)(embb + (((unsigned int)n1.z << 7) + dd));
        unsigned short h7 = *(const unsigned short*)(embb + (((unsigned int)n1.w << 7) + dd));
        uint4v pk;
        pk.x = (unsigned int)h0 | ((unsigned int)h1 << 16);
        pk.y = (unsigned int)h2 | ((unsigned int)h3 << 16);
        pk.z = (unsigned int)h4 | ((unsigned int)h5 << 16);
        pk.w = (unsigned int)h6 | ((unsigned int)h7 << 16);
        short8 bf = __builtin_bit_cast(short8, pk);
        acc = __builtin_amdgcn_mfma_f32_16x16x32_bf16(a, bf, acc, 0, 0, 0);
      }
#pragma unroll
      for (int r = 0; r < 4; ++r)
        S[(w * 16 + quad * 4 + r) * XS + xc0 + nt * 16 + l15] = f2bf(acc[r]);
    }
  }

  // ---- MLP: wave-private 16-row bands, no barriers. Aliasing inside X:
  // L1 reads cols 0..127 -> writes 0..63; L2 reads 0..63 -> writes 64..127;
  // L3 reads 64..127 -> writes 0..31; L4+L5 in registers.
  const unsigned short* xrow = S + (w * 16 + l15) * XS;
  {
    short8 a[4];
#pragma unroll
    for (int k = 0; k < 4; ++k)
      a[k] = *reinterpret_cast<const short8*>(xrow + k * 32 + quad * 8);
    mlp_layer<4, 4>(a, ws + W1_OFF, b1, S, 0, w, l15, quad, lane);
  }
  {
    short8 a[2];
    a[0] = *reinterpret_cast<const short8*>(xrow + quad * 8);
    a[1] = *reinterpret_cast<const short8*>(xrow + 32 + quad * 8);
    mlp_layer<4, 2>(a, ws + W2_OFF, b2, S, 64, w, l15, quad, lane);
  }
  {
    short8 a[2];
    a[0] = *reinterpret_cast<const short8*>(xrow + 64 + quad * 8);
    a[1] = *reinterpret_cast<const short8*>(xrow + 96 + quad * 8);
    mlp_layer<2, 2>(a, ws + W3_OFF, b3, S, 0, w, l15, quad, lane);
  }
  // L4 (32->32, relu) fused with L5 (32->1) + sigmoid + partial mean
  {
    short8 a = *reinterpret_cast<const short8*>(xrow + quad * 8);
    float dot[4] = {0.f, 0.f, 0.f, 0.f};
#pragma unroll
    for (int n = 0; n < 2; ++n) {
      f32x4 acc = {0.f, 0.f, 0.f, 0.f};
      short8 bf = *reinterpret_cast<const short8*>(ws + W4_OFF + (n * 64 + lane) * 8);
      acc = __builtin_amdgcn_mfma_f32_16x16x32_bf16(a, bf, acc, 0, 0, 0);
      const int col = n * 16 + l15;
      const float bv = b4[col], wv = w5[col];
#pragma unroll
      for (int r = 0; r < 4; ++r) {
        float v = fmaxf(acc[r] + bv, 0.f);
        dot[r] = fmaf(v, wv, dot[r]);
      }
    }
    float wsum = 0.f;
    const float bb5 = b5[0];
#pragma unroll
    for (int r = 0; r < 4; ++r) {
      float s = dot[r];
      s += __shfl_xor(s, 1, 64);
      s += __shfl_xor(s, 2, 64);
      s += __shfl_xor(s, 4, 64);
      s += __shfl_xor(s, 8, 64);
      const int row = w * 16 + quad * 4 + r;
      if (l15 == 0 && row < KN) wsum += 1.f / (1.f + expf(-(s + bb5)));
    }
    wsum += __shfl_xor(wsum, 16, 64);
    wsum += __shfl_xor(wsum, 32, 64);
    if (lane == 0) s_red[w] = wsum;
  }
  __syncthreads();  // barrier #2
  if (tid == 0) {
    float t = 0.f;
#pragma unroll
    for (int i = 0; i < 7; ++i) t += s_red[i];
    out[b] = t * (1.0f / KN);
  }
}

extern "C" void kernel_launch(void* const* d_in, const int* in_sizes, int n_in,
                              void* d_out, int out_size, void* d_ws,
                              size_t ws_size, hipStream_t stream) {
  const float* user_emb = (const float*)d_in[0];
  const float* item_emb = (const float*)d_in[1];
  const float* user_scr = (const float*)d_in[2];
  const float* item_scr = (const float*)d_in[3];
  const float* w1 = (const float*)d_in[4];
  const float* b1 = (const float*)d_in[5];
  const float* w2 = (const float*)d_in[6];
  const float* b2 = (const float*)d_in[7];
  const float* w3 = (const float*)d_in[8];
  const float* b3 = (const float*)d_in[9];
  const float* w4 = (const float*)d_in[10];
  const float* b4 = (const float*)d_in[11];
  const float* w5 = (const float*)d_in[12];
  const float* b5 = (const float*)d_in[13];
  const int* user_idx_t = (const int*)d_in[14];
  const int* item_idx_t = (const int*)d_in[15];
  const int* user_idxs = (const int*)d_in[16];
  const int* item_idxs = (const int*)d_in[17];
  unsigned short* wsw = (unsigned short*)d_ws;

  prep<<<dim3((15360 + 2400000 + 1200000 + 255) / 256), dim3(256), 0, stream>>>(
      w1, w2, w3, w4, user_scr, item_scr, user_emb, item_emb, wsw);

  const int B = in_sizes[16];  // 8192
  cnn_mfma4<<<dim3(B), dim3(448), 0, stream>>>(
      wsw, b1, b2, b3, b4, w5, b5, user_idx_t, item_idx_t, user_idxs,
      item_idxs, (float*)d_out);
}

// Round 6
// 401.554 us; speedup vs baseline: 1.4500x; 1.4500x over previous
//
#include <hip/hip_runtime.h>
#include <hip/hip_bf16.h>
#include <math.h>

typedef __attribute__((ext_vector_type(8))) short short8;
typedef __attribute__((ext_vector_type(4))) float f32x4;

#define KN 100

// ---- ws layout (halfword units) ----
#define W1_OFF 0         // 64x128 bf16, B-frag swizzled, kt=4
#define W2_OFF 8192      // 64x64, kt=2
#define W3_OFF 12288     // 32x64, kt=2
#define W4_OFF 14336     // 32x32, kt=1
#define SCRU_OFF 16384                        // 100000 x 128 bf16 (zero-padded j>=100)
#define SCRI_OFF (SCRU_OFF + 100000 * 128)    // 50000 x 128
#define EMBU_OFF (SCRI_OFF + 50000 * 128)     // 100000 x 64 bf16
#define EMBI_OFF (EMBU_OFF + 100000 * 64)     // 50000 x 64
#define NB_OFF   (EMBI_OFF + 50000 * 64)      // int32[8192][256]: resolved nb lists
// end: NB_OFF + 2*2097152 hw = 66.0 MB

// ---- LDS layout (halfword offsets) ----
#define ETU 0            // 64 x 136  (user E^T)
#define ETI 8704         // 64 x 136  (item E^T)
#define XU  17408        // 112 x 72  (pooled user; MLP Y1/Y3 alias per-band)
#define XI  8704         // 112 x 72  (pooled item; aliases ETI after barrier 2)
#define S_TOT 25472      // 50944 B

__device__ __forceinline__ unsigned short f2bf(float f) {
  __hip_bfloat16 h = __float2bfloat16(f);
  return __builtin_bit_cast(unsigned short, h);
}

__device__ __forceinline__ void st8(unsigned short* d, float4 a, float4 b) {
  short8 h;
  h[0] = (short)f2bf(a.x); h[1] = (short)f2bf(a.y);
  h[2] = (short)f2bf(a.z); h[3] = (short)f2bf(a.w);
  h[4] = (short)f2bf(b.x); h[5] = (short)f2bf(b.y);
  h[6] = (short)f2bf(b.z); h[7] = (short)f2bf(b.w);
  *reinterpret_cast<short8*>(d) = h;
}

// Streaming prep: weights (B-frag swizzle) + scr (bf16, pad to 128) + emb (bf16)
// + resolved neighbor lists nb[b][256] (user 0-127, item 128-255; pad rows -> 0).
__global__ void prep(const float* __restrict__ w1, const float* __restrict__ w2,
                     const float* __restrict__ w3, const float* __restrict__ w4,
                     const float* __restrict__ uscr, const float* __restrict__ iscr,
                     const float* __restrict__ uemb, const float* __restrict__ iemb,
                     const int* __restrict__ uidx_t, const int* __restrict__ iidx_t,
                     const int* __restrict__ uidxs, const int* __restrict__ iidxs,
                     unsigned short* __restrict__ ws) {
  int t = blockIdx.x * 256 + threadIdx.x;
  if (t < 15360) {
    const float* src; int rel, o, i, kt, base;
    if (t < 8192)       { src = w1; rel = t;         o = rel >> 7; i = rel & 127; kt = 4; base = W1_OFF; }
    else if (t < 12288) { src = w2; rel = t - 8192;  o = rel >> 6; i = rel & 63;  kt = 2; base = W2_OFF; }
    else if (t < 14336) { src = w3; rel = t - 12288; o = rel >> 6; i = rel & 63;  kt = 2; base = W3_OFF; }
    else                { src = w4; rel = t - 14336; o = rel >> 5; i = rel & 31;  kt = 1; base = W4_OFF; }
    int n = o >> 4, l15 = o & 15, k = i >> 5, quad = (i >> 3) & 3, j = i & 7;
    ws[base + ((n * kt + k) * 64 + quad * 16 + l15) * 8 + j] = f2bf(src[rel]);
    return;
  }
  int rel = t - 15360;
  const float4 z4 = {0.f, 0.f, 0.f, 0.f};
  if (rel < 2400000) {  // scr: 16 threads/row, 8 cols each (pad >=100 with 0)
    const float* src; unsigned short* dst; int row, g;
    if (rel < 1600000) {
      row = rel >> 4; g = rel & 15;
      src = uscr + (size_t)row * 100;
      dst = ws + SCRU_OFF + (size_t)row * 128 + g * 8;
    } else {
      int q = rel - 1600000; row = q >> 4; g = q & 15;
      src = iscr + (size_t)row * 100;
      dst = ws + SCRI_OFF + (size_t)row * 128 + g * 8;
    }
    float4 va = (g < 13) ? *reinterpret_cast<const float4*>(src + g * 8) : z4;
    float4 vb = (g < 12) ? *reinterpret_cast<const float4*>(src + g * 8 + 4) : z4;
    st8(dst, va, vb);
    return;
  }
  rel -= 2400000;
  if (rel < 1200000) {  // emb: 8 threads/row, 8 cols each
    const float* src; unsigned short* dst; int row, g;
    if (rel < 800000) {
      row = rel >> 3; g = rel & 7;
      src = uemb + (size_t)row * 64;
      dst = ws + EMBU_OFF + (size_t)row * 64 + g * 8;
    } else {
      int q = rel - 800000; row = q >> 3; g = q & 7;
      src = iemb + (size_t)row * 64;
      dst = ws + EMBI_OFF + (size_t)row * 64 + g * 8;
    }
    float4 va = *reinterpret_cast<const float4*>(src + g * 8);
    float4 vb = *reinterpret_cast<const float4*>(src + g * 8 + 4);
    st8(dst, va, vb);
    return;
  }
  rel -= 1200000;
  if (rel < 2097152) {  // nb resolve: removes one indirection level from main
    const int b = rel >> 8, i = rel & 255;
    int v;
    if (i < 128) {
      v = (i < KN) ? uidx_t[(size_t)uidxs[b] * KN + i] : 0;
    } else {
      const int j = i - 128;
      v = (j < KN) ? iidx_t[(size_t)iidxs[b] * KN + j] : 0;
    }
    ((int*)(ws + NB_OFF))[rel] = v;
  }
}

// One MLP layer for wave w's 16-row band: Y = relu(A @ W^T + bias), stride 72.
template <int NT, int KT>
__device__ __forceinline__ void mlp_layer(const short8* a,
                                          const unsigned short* __restrict__ gw,
                                          const float* __restrict__ bias,
                                          unsigned short* __restrict__ Y,
                                          int w, int l15, int quad, int lane) {
#pragma unroll
  for (int n = 0; n < NT; ++n) {
    f32x4 acc = {0.f, 0.f, 0.f, 0.f};
#pragma unroll
    for (int k = 0; k < KT; ++k) {
      short8 bf = *reinterpret_cast<const short8*>(gw + ((n * KT + k) * 64 + lane) * 8);
      acc = __builtin_amdgcn_mfma_f32_16x16x32_bf16(a[k], bf, acc, 0, 0, 0);
    }
    const int col = n * 16 + l15;
    const float bv = bias[col];
#pragma unroll
    for (int r = 0; r < 4; ++r) {
      float v = fmaxf(acc[r] + bv, 0.f);
      Y[(w * 16 + quad * 4 + r) * 72 + col] = f2bf(v);
    }
  }
}

__launch_bounds__(448, 6)
__global__ void cnn_mfma5(
    const unsigned short* __restrict__ ws,
    const float* __restrict__ b1, const float* __restrict__ b2,
    const float* __restrict__ b3, const float* __restrict__ b4,
    const float* __restrict__ w5, const float* __restrict__ b5,
    float* __restrict__ out) {
  __shared__ __align__(16) unsigned short S[S_TOT];
  __shared__ float s_red[7];

  const int b = blockIdx.x;
  const int tid = threadIdx.x;
  const int w = tid >> 6;
  const int lane = tid & 63;
  const int l15 = lane & 15, quad = lane >> 4;
  const int c = lane & 31, half = lane >> 5;

  const int* nbu = (const int*)(ws + NB_OFF) + (size_t)b * 256;
  const int* nbi = nbu + 128;
  const char* scru = (const char*)(ws + SCRU_OFF);
  const char* scri = (const char*)(ws + SCRI_OFF);
  const char* embu = (const char*)(ws + EMBU_OFF);
  const char* embi = (const char*)(ws + EMBI_OFF);

  // ---- single memory epoch: all gathers issue here, no barriers between ----
  const int mu = nbu[w * 16 + l15];  // A-row indices (coalesced 64B per 16 lanes)
  const int mi = nbi[w * 16 + l15];

  short8 au[4], ai[4];
#pragma unroll
  for (int k = 0; k < 4; ++k)
    au[k] = *reinterpret_cast<const short8*>(scru + ((size_t)(unsigned)mu << 8) + k * 64 + quad * 16);
#pragma unroll
  for (int k = 0; k < 4; ++k)
    ai[k] = *reinterpret_cast<const short8*>(scri + ((size_t)(unsigned)mi << 8) + k * 64 + quad * 16);

  // Et staging loads, both sources (wave w rows: r = 2*(w+rr*7)+half)
  unsigned int du[8], di[8];
  int rv[8];
#pragma unroll
  for (int rr = 0; rr < 8; ++rr) {
    const int rbase = w + rr * 7;
    if (rbase < 50) {
      const int r = rbase * 2 + half;
      rv[rr] = r;
      du[rr] = *reinterpret_cast<const unsigned int*>(
          embu + ((size_t)(unsigned)nbu[r] << 7) + c * 4);
      di[rr] = *reinterpret_cast<const unsigned int*>(
          embi + ((size_t)(unsigned)nbi[r] << 7) + c * 4);
    }
  }
  // zero Et k-pads (j in [100,128)) while the loads fly (0*garbage != 0 if NaN)
  for (int q = tid; q < 1792; q += 448) {
    const int buf = q / 896, rem = q - buf * 896;
    const int row = rem / 14, cp = rem - row * 14;
    *reinterpret_cast<unsigned int*>(&S[buf * 8704 + row * 136 + 100 + cp * 2]) = 0u;
  }
  // transposed bf16 stores into Et_u / Et_i
#pragma unroll
  for (int rr = 0; rr < 8; ++rr) {
    const int rbase = w + rr * 7;
    if (rbase < 50) {
      const int r = rv[rr];
      S[ETU + (2 * c) * 136 + r] = (unsigned short)(du[rr] & 0xffffu);
      S[ETU + (2 * c + 1) * 136 + r] = (unsigned short)(du[rr] >> 16);
      S[ETI + (2 * c) * 136 + r] = (unsigned short)(di[rr] & 0xffffu);
      S[ETI + (2 * c + 1) * 136 + r] = (unsigned short)(di[rr] >> 16);
    }
  }
  __syncthreads();  // barrier 1 — the only one guarding a memory epoch

  // ---- user pool -> Xu (own region, no barrier needed) ----
#pragma unroll
  for (int nt = 0; nt < 4; ++nt) {
    f32x4 acc = {0.f, 0.f, 0.f, 0.f};
#pragma unroll
    for (int kt = 0; kt < 4; ++kt) {
      short8 bf = *reinterpret_cast<const short8*>(
          S + ETU + (nt * 16 + l15) * 136 + kt * 32 + quad * 8);
      acc = __builtin_amdgcn_mfma_f32_16x16x32_bf16(au[kt], bf, acc, 0, 0, 0);
    }
#pragma unroll
    for (int r = 0; r < 4; ++r)
      S[XU + (w * 16 + quad * 4 + r) * 72 + nt * 16 + l15] = f2bf(acc[r]);
  }

  // ---- item pool -> registers (Xi region still holds Et_i) ----
  f32x4 acci[4];
#pragma unroll
  for (int nt = 0; nt < 4; ++nt) {
    f32x4 acc = {0.f, 0.f, 0.f, 0.f};
#pragma unroll
    for (int kt = 0; kt < 4; ++kt) {
      short8 bf = *reinterpret_cast<const short8*>(
          S + ETI + (nt * 16 + l15) * 136 + kt * 32 + quad * 8);
      acc = __builtin_amdgcn_mfma_f32_16x16x32_bf16(ai[kt], bf, acc, 0, 0, 0);
    }
    acci[nt] = acc;
  }
  __syncthreads();  // barrier 2 — all Et_i reads done; Xi may overwrite it

#pragma unroll
  for (int nt = 0; nt < 4; ++nt)
#pragma unroll
    for (int r = 0; r < 4; ++r)
      S[XI + (w * 16 + quad * 4 + r) * 72 + nt * 16 + l15] = f2bf(acci[nt][r]);

  // ---- MLP: wave-private 16-row bands, no barriers.
  // L1 reads Xu+Xi -> writes over Xu band; L2 reads Xu -> Xi band;
  // L3 reads Xi -> Xu band; L4+L5 in registers.
  const unsigned short* xu_row = S + XU + (w * 16 + l15) * 72;
  const unsigned short* xi_row = S + XI + (w * 16 + l15) * 72;
  {
    short8 a[4];
    a[0] = *reinterpret_cast<const short8*>(xu_row + quad * 8);
    a[1] = *reinterpret_cast<const short8*>(xu_row + 32 + quad * 8);
    a[2] = *reinterpret_cast<const short8*>(xi_row + quad * 8);
    a[3] = *reinterpret_cast<const short8*>(xi_row + 32 + quad * 8);
    mlp_layer<4, 4>(a, ws + W1_OFF, b1, S + XU, w, l15, quad, lane);
  }
  {
    short8 a[2];
    a[0] = *reinterpret_cast<const short8*>(xu_row + quad * 8);
    a[1] = *reinterpret_cast<const short8*>(xu_row + 32 + quad * 8);
    mlp_layer<4, 2>(a, ws + W2_OFF, b2, S + XI, w, l15, quad, lane);
  }
  {
    short8 a[2];
    a[0] = *reinterpret_cast<const short8*>(xi_row + quad * 8);
    a[1] = *reinterpret_cast<const short8*>(xi_row + 32 + quad * 8);
    mlp_layer<2, 2>(a, ws + W3_OFF, b3, S + XU, w, l15, quad, lane);
  }
  // L4 (32->32, relu) fused with L5 (32->1) + sigmoid + partial mean
  {
    short8 a = *reinterpret_cast<const short8*>(xu_row + quad * 8);
    float dot[4] = {0.f, 0.f, 0.f, 0.f};
#pragma unroll
    for (int n = 0; n < 2; ++n) {
      f32x4 acc = {0.f, 0.f, 0.f, 0.f};
      short8 bf = *reinterpret_cast<const short8*>(ws + W4_OFF + (n * 64 + lane) * 8);
      acc = __builtin_amdgcn_mfma_f32_16x16x32_bf16(a, bf, acc, 0, 0, 0);
      const int col = n * 16 + l15;
      const float bv = b4[col], wv = w5[col];
#pragma unroll
      for (int r = 0; r < 4; ++r) {
        float v = fmaxf(acc[r] + bv, 0.f);
        dot[r] = fmaf(v, wv, dot[r]);
      }
    }
    float wsum = 0.f;
    const float bb5 = b5[0];
#pragma unroll
    for (int r = 0; r < 4; ++r) {
      float s = dot[r];
      s += __shfl_xor(s, 1, 64);
      s += __shfl_xor(s, 2, 64);
      s += __shfl_xor(s, 4, 64);
      s += __shfl_xor(s, 8, 64);
      const int row = w * 16 + quad * 4 + r;
      if (l15 == 0 && row < KN) wsum += 1.f / (1.f + expf(-(s + bb5)));
    }
    wsum += __shfl_xor(wsum, 16, 64);
    wsum += __shfl_xor(wsum, 32, 64);
    if (lane == 0) s_red[w] = wsum;
  }
  __syncthreads();  // barrier 3
  if (tid == 0) {
    float t = 0.f;
#pragma unroll
    for (int i = 0; i < 7; ++i) t += s_red[i];
    out[b] = t * (1.0f / KN);
  }
}

extern "C" void kernel_launch(void* const* d_in, const int* in_sizes, int n_in,
                              void* d_out, int out_size, void* d_ws,
                              size_t ws_size, hipStream_t stream) {
  const float* user_emb = (const float*)d_in[0];
  const float* item_emb = (const float*)d_in[1];
  const float* user_scr = (const float*)d_in[2];
  const float* item_scr = (const float*)d_in[3];
  const float* w1 = (const float*)d_in[4];
  const float* b1 = (const float*)d_in[5];
  const float* w2 = (const float*)d_in[6];
  const float* b2 = (const float*)d_in[7];
  const float* w3 = (const float*)d_in[8];
  const float* b3 = (const float*)d_in[9];
  const float* w4 = (const float*)d_in[10];
  const float* b4 = (const float*)d_in[11];
  const float* w5 = (const float*)d_in[12];
  const float* b5 = (const float*)d_in[13];
  const int* user_idx_t = (const int*)d_in[14];
  const int* item_idx_t = (const int*)d_in[15];
  const int* user_idxs = (const int*)d_in[16];
  const int* item_idxs = (const int*)d_in[17];
  unsigned short* wsw = (unsigned short*)d_ws;

  // 15360 (weights) + 2.4M (scr) + 1.2M (emb) + 2.097M (nb) threads
  const int prep_threads = 15360 + 2400000 + 1200000 + 2097152;
  prep<<<dim3((prep_threads + 255) / 256), dim3(256), 0, stream>>>(
      w1, w2, w3, w4, user_scr, item_scr, user_emb, item_emb,
      user_idx_t, item_idx_t, user_idxs, item_idxs, wsw);

  const int B = in_sizes[16];  // 8192
  cnn_mfma5<<<dim3(B), dim3(448), 0, stream>>>(
      wsw, b1, b2, b3, b4, w5, b5, (float*)d_out);
}